// Round 7
// baseline (228.202 us; speedup 1.0000x reference)
//
#include <hip/hip_runtime.h>
#include <math.h>

#define B 16
#define D 8
#define FDIM 2
#define N 512
#define E 10            // D + FDIM
#define NP36 36         // pairs a<=d
#define GJW (2*E)       // augmented width for Gauss-Jordan
#define NT 4            // i-tiles per (pair,b)
#define TIL 128         // i-tile size
#define NQ (NP36*B*NT)        // 2304 k_q blocks
#define NPREP (NP36*B + B*D)  // 576 pair + 128 A blocks
#define LOG2E 1.44269504088896340736f

// ---- workspace layout (float offsets) ----
#define OFF_MUD    0         // B*D         = 128
#define OFF_V      128       // B*D*E       = 1280
#define OFF_EDD    1408      // B*D*D       = 1024 (atomic-accumulated)
#define OFF_TR     2432      // B*D         = 128  (atomic-accumulated)
#define OFF_TICKET 2560      // 1 (int)
#define OFF_XNU    2564      // B*N*12      = 98304  [x0..x9,1,0] (16B-aligned)
#define OFF_WMAT   100868    // NP36*B*304  = 175104 [W 100][Wa' 100][Wd' 100][base_a][base_d][pad]
// total 275972 floats = 1.10 MB

__device__ __forceinline__ void decode_pair(int p36, int* pa, int* pd) {
  int a = 0, rem = p36;
  while (rem >= D - a) { rem -= (D - a); a++; }
  *pa = a; *pd = a + rem;
}

__device__ __forceinline__ float wave_reduce(float v) {
#pragma unroll
  for (int off = 32; off > 0; off >>= 1) v += __shfl_down(v, off);
  return v;
}

__device__ __forceinline__ float fast_exp2(float x) {
#if __has_builtin(__builtin_amdgcn_exp2f)
  return __builtin_amdgcn_exp2f(x);
#else
  return exp2f(x);
#endif
}

// Single-wave Gauss-Jordan with partial pivoting on augmented E x GJW system
// in LDS. Call from ALL threads; only wave 0 acts. Caller must __syncthreads()
// after. Returns log|det(left)| on wave 0 lanes.
__device__ __forceinline__ float gj_wave(float (*M)[GJW], float* colfac,
                                         int tid) {
  float detprod = 1.0f;
  if (tid < 64) {
    int lane = tid;
    for (int k = 0; k < E; k++) {
      float v = (lane < E && lane >= k) ? fabsf(M[lane][k]) : -1.0f;
      int idx = lane;
#pragma unroll
      for (int off = 8; off > 0; off >>= 1) {
        float ov = __shfl_xor(v, off);
        int oi = __shfl_xor(idx, off);
        if (ov > v) { v = ov; idx = oi; }
      }
      int pr = __shfl(idx, 0);
      float piv = M[pr][k];
      detprod *= fabsf(piv);
      if (lane < GJW) {
        float rowp = M[pr][lane];
        float rowk = M[k][lane];
        M[pr][lane] = rowk;
        M[k][lane] = rowp / piv;
      }
      if (lane < E) colfac[lane] = M[lane][k];
      for (int i2 = lane; i2 < E * GJW; i2 += 64) {
        int r = i2 / GJW, c = i2 % GJW;
        if (r != k) M[r][c] -= colfac[r] * M[k][c];
      }
    }
  }
  return logf(detprod);
}

// ---------------------------------------------------------------------------
// k_prep: blocks [0, NP36*B): per-(pair,b) GJ -> W/Wa'/Wd' + base scalars.
//         blocks [NP36*B, +B*D): mu_delta[b,d], V[b,d,:] (+XNU when d==0).
//         block 0 additionally zeroes EDD/TR/ticket.
__global__ __launch_bounds__(256) void k_prep(
    const float* __restrict__ obs_mean, const float* __restrict__ obs_var,
    const float* __restrict__ action_mean, const float* __restrict__ action_var,
    const float* __restrict__ cross_cov, const float* __restrict__ X,
    const float* __restrict__ ell, const float* __restrict__ alpha_sq,
    const float* __restrict__ beta, float* __restrict__ ws) {
  __shared__ float M[E][GJW];
  __shared__ float colfac[E];
  __shared__ float s_logdet, s_ldl;
  __shared__ float sMu[E], sSig[E * E], siLa[E], siLd[E];
  __shared__ float wred[4][11];
  __shared__ float wsh[E];

  int tid = threadIdx.x;
  int bx = blockIdx.x;

  if (bx >= NP36 * B) {
    // ===== A-path: mu_delta[b,d], V[b,d,:] =====
    int bd = bx - NP36 * B;
    int b = bd / D, d = bd % D;
    if (tid < E) {
      sMu[tid] = (tid < D) ? obs_mean[b * D + tid] : action_mean[b * FDIM + tid - D];
    }
    for (int idx = tid; idx < E * E; idx += 256) {
      int e = idx / E, f = idx % E;
      float v;
      if (e < D && f < D)      v = obs_var[(b * D + e) * D + f];
      else if (e < D)          v = cross_cov[(b * D + e) * FDIM + (f - D)];
      else if (f < D)          v = cross_cov[(b * D + f) * FDIM + (e - D)];
      else                     v = action_var[(b * FDIM + (e - D)) * FDIM + (f - D)];
      sSig[idx] = v;
    }
    __syncthreads();
    for (int idx = tid; idx < E * GJW; idx += 256) {
      int r = idx / GJW, c = idx % GJW;
      float v;
      if (c < E) {
        v = sSig[r * E + c];
        if (r == c) { float l = ell[d * E + r]; v += l * l; }
      } else {
        v = (c - E == r) ? 1.0f : 0.0f;
      }
      M[r][c] = v;
    }
    if (tid == 64) {
      float s = 0.0f;
#pragma unroll
      for (int e = 0; e < E; e++) { float l = ell[d * E + e]; s += logf(l * l); }
      s_ldl = s;
    }
    __syncthreads();
    float ld = gj_wave(M, colfac, tid);   // M[r][E+c] = Ainv
    if (tid == 0) s_logdet = ld;
    __syncthreads();
    float c0 = 0.5f * (s_ldl - s_logdet);
    float a2 = alpha_sq[d];
    float acc_mu = 0.0f, acc_w[E];
#pragma unroll
    for (int e = 0; e < E; e++) acc_w[e] = 0.0f;
    bool wx = (d == 0);
    for (int n = tid; n < N; n += 256) {
      float x[E];
#pragma unroll
      for (int e = 0; e < E; e++) x[e] = X[n * E + e] - sMu[e];
      if (wx) {
        float* xr = ws + OFF_XNU + ((size_t)b * N + n) * 12;
#pragma unroll
        for (int e = 0; e < E; e++) xr[e] = x[e];
        xr[10] = 1.0f; xr[11] = 0.0f;
      }
      float quad = 0.0f;
#pragma unroll
      for (int e = 0; e < E; e++) {
        float te = 0.0f;
#pragma unroll
        for (int f = 0; f < E; f++) te += M[e][E + f] * x[f];
        quad += x[e] * te;
      }
      float qval = a2 * __expf(c0 - 0.5f * quad);
      float bq = beta[d * N + n] * qval;
      acc_mu += bq;
#pragma unroll
      for (int e = 0; e < E; e++) acc_w[e] += bq * x[e];
    }
    int wid = tid >> 6, lane = tid & 63;
    float r = wave_reduce(acc_mu);
    if (lane == 0) wred[wid][0] = r;
#pragma unroll
    for (int e = 0; e < E; e++) {
      r = wave_reduce(acc_w[e]);
      if (lane == 0) wred[wid][e + 1] = r;
    }
    __syncthreads();
    if (tid < 11) {
      float s = wred[0][tid] + wred[1][tid] + wred[2][tid] + wred[3][tid];
      if (tid == 0) ws[OFF_MUD + b * D + d] = s;
      else wsh[tid - 1] = s;
    }
    __syncthreads();
    if (tid == 0) {
      float u[E];
#pragma unroll
      for (int f = 0; f < E; f++) {
        float s = 0.0f;
#pragma unroll
        for (int g = 0; g < E; g++) s += M[f][E + g] * wsh[g];
        u[f] = s;
      }
#pragma unroll
      for (int e = 0; e < E; e++) {
        float s = 0.0f;
#pragma unroll
        for (int f = 0; f < E; f++) s += sSig[e * E + f] * u[f];
        ws[OFF_V + (b * D + d) * E + e] = s;
      }
    }
    return;
  }

  // ===== pair path: W matrices for (p36, b) =====
  if (bx == 0) {   // zero EDD(1024)+TR(128)+ticket(1) before k_q
    for (int idx = tid; idx < 1153; idx += 256) ws[OFF_EDD + idx] = 0.0f;
  }
  int p36 = bx / B, b = bx % B;
  int a, d;
  decode_pair(p36, &a, &d);
  int pb = p36 * B + b;
  if (tid < E) {
    float la = ell[a * E + tid]; siLa[tid] = 1.0f / (la * la);
    float ldv = ell[d * E + tid]; siLd[tid] = 1.0f / (ldv * ldv);
  }
  for (int idx = tid; idx < E * E; idx += 256) {
    int e = idx / E, f = idx % E;
    float v;
    if (e < D && f < D)      v = obs_var[(b * D + e) * D + f];
    else if (e < D)          v = cross_cov[(b * D + e) * FDIM + (f - D)];
    else if (f < D)          v = cross_cov[(b * D + f) * FDIM + (e - D)];
    else                     v = action_var[(b * FDIM + (e - D)) * FDIM + (f - D)];
    sSig[idx] = v;
  }
  __syncthreads();
  for (int idx = tid; idx < E * GJW; idx += 256) {
    int r = idx / GJW, c = idx % GJW;
    float v;
    if (c < E) v = sSig[r * E + c] * (siLa[c] + siLd[c]) + ((r == c) ? 1.0f : 0.0f);
    else       v = sSig[r * E + (c - E)];
    M[r][c] = v;
  }
  __syncthreads();
  float ld = gj_wave(M, colfac, tid);    // M[r][E+c] = S, ld = logdetR
  if (tid == 0) s_logdet = ld;
  __syncthreads();
  float ldr = s_logdet;
  float* Wp = ws + OFF_WMAT + (size_t)pb * 304;
  for (int idx = tid; idx < E * E; idx += 256) {
    int e = idx / E, f = idx % E;
    float S = M[e][E + f];
    Wp[idx] = LOG2E * siLa[e] * S * siLd[f];
    float wa = LOG2E * siLa[e] * S * siLa[f];
    if (e == f) wa -= LOG2E * siLa[e];
    Wp[100 + idx] = wa;
    float wd = LOG2E * siLd[e] * S * siLd[f];
    if (e == f) wd -= LOG2E * siLd[e];
    Wp[200 + idx] = wd;
  }
  if (tid == 0) {
    Wp[300] = LOG2E * (logf(alpha_sq[a]) - 0.5f * ldr);   // base_a
    Wp[301] = LOG2E * logf(alpha_sq[d]);                  // base_d
  }
}

// ---------------------------------------------------------------------------
// k_q: per (pair, b, i-tile). Lane holds 2 T-rows in registers; j-data
// streams from LDS as wave-uniform b128 broadcasts. Waves split j-range.
// Last block (ticket) assembles the final output.
__global__ __launch_bounds__(256) void k_q(
    const float* __restrict__ obs_mean, const float* __restrict__ obs_var,
    const float* __restrict__ alpha_sq, const float* __restrict__ sigma_sq_eps,
    const float* __restrict__ beta, const float* __restrict__ invK,
    float* __restrict__ ws, float* __restrict__ out) {
  __shared__ float sxj[N * 12];      // 24576 B: [x0..x9, fb, cbE] per j
  __shared__ float sT[TIL * 12];     // 6144 B:  [t0..t9, baE, Ei] per i-row
  __shared__ float sW[100], sWa[100], sWd[100];
  __shared__ float s_base[2];
  __shared__ float redw[8];
  __shared__ int s_last;

  int tid = threadIdx.x;
  int bx = blockIdx.x;
  int tile = bx & (NT - 1);
  int rest = bx >> 2;
  int b = rest & (B - 1);
  int p36 = rest >> 4;
  int a, d;
  decode_pair(p36, &a, &d);
  int pb = p36 * B + b;
  bool diag = (a == d);
  int i0 = tile * TIL;

  // ---- phase A0: load W matrices ----
  {
    const float* Wp = ws + OFF_WMAT + (size_t)pb * 304;
    for (int idx = tid; idx < 100; idx += 256) {
      sW[idx] = Wp[idx];
      sWa[idx] = Wp[100 + idx];
      sWd[idx] = Wp[200 + idx];
    }
    if (tid == 0) { s_base[0] = Wp[300]; s_base[1] = Wp[301]; }
  }
  __syncthreads();
  float base_a = s_base[0], base_d = s_base[1];

  // ---- phase A1: build sxj rows [x, fb, cbE] for all 512 j ----
  for (int j = tid; j < N; j += 256) {
    const float4* xp = (const float4*)(ws + OFF_XNU + ((size_t)b * N + j) * 12);
    float4 a0 = xp[0], a1 = xp[1], a2 = xp[2];
    float x[10] = {a0.x, a0.y, a0.z, a0.w, a1.x, a1.y, a1.z, a1.w, a2.x, a2.y};
    float q = 0.0f;
#pragma unroll
    for (int e = 0; e < E; e++) {
      float te = 0.0f;
#pragma unroll
      for (int f = 0; f < E; f++) te += sWd[e * 10 + f] * x[f];
      q += x[e] * te;
    }
    float cbE = fast_exp2(base_d + 0.5f * q);
    float fb = beta[(size_t)d * N + j] * cbE;
    float4* s4 = (float4*)(sxj + j * 12);
    s4[0] = a0;
    s4[1] = a1;
    s4[2] = make_float4(a2.x, a2.y, fb, cbE);
  }
  __syncthreads();

  // ---- phase B: build sT rows [t, baE, Ei] for own 128 i ----
  for (int idx = tid; idx < TIL * E; idx += 256) {
    int il = idx / E, f = idx % E;
    const float* x = sxj + (i0 + il) * 12;
    float acc = 0.0f;
#pragma unroll
    for (int e = 0; e < E; e++) acc += x[e] * sW[e * 10 + f];
    sT[il * 12 + f] = acc;
  }
  if (tid < TIL) {
    const float* x = sxj + (i0 + tid) * 12;
    float q = 0.0f;
#pragma unroll
    for (int e = 0; e < E; e++) {
      float te = 0.0f;
#pragma unroll
      for (int f = 0; f < E; f++) te += sWa[e * 10 + f] * x[f];
      q += x[e] * te;
    }
    float Ei = fast_exp2(base_a + 0.5f * q);
    sT[tid * 12 + 10] = beta[(size_t)a * N + i0 + tid] * Ei;
    sT[tid * 12 + 11] = Ei;
  }
  __syncthreads();

  // ---- main loop: lane = 2 i-rows (regs), wave = j-quarter (LDS bcast) ----
  int lane = tid & 63;
  int wv = tid >> 6;
  int r0 = lane * 2;
  float4 ta0, ta1, ta2, tb0, tb1, tb2;
  {
    const float4* tp = (const float4*)(sT + r0 * 12);
    ta0 = tp[0]; ta1 = tp[1]; ta2 = tp[2];
    tb0 = tp[3]; tb1 = tp[4]; tb2 = tp[5];
  }
  const float* invKrow = invK + (size_t)a * N * N;
  int iA = i0 + r0;
  float raccA = 0.0f, raccB = 0.0f, traccA = 0.0f, traccB = 0.0f;
  const float4* sx4 = (const float4*)sxj;
  int jw = wv * 128;
#pragma unroll 2
  for (int jj = 0; jj < 128; jj++) {
    int j = jw + jj;
    float4 x0 = sx4[j * 3], x1 = sx4[j * 3 + 1], x2 = sx4[j * 3 + 2];
    float mA = ta0.x * x0.x;
    mA = fmaf(ta0.y, x0.y, mA); mA = fmaf(ta0.z, x0.z, mA);
    mA = fmaf(ta0.w, x0.w, mA); mA = fmaf(ta1.x, x1.x, mA);
    mA = fmaf(ta1.y, x1.y, mA); mA = fmaf(ta1.z, x1.z, mA);
    mA = fmaf(ta1.w, x1.w, mA); mA = fmaf(ta2.x, x2.x, mA);
    mA = fmaf(ta2.y, x2.y, mA);
    float mB = tb0.x * x0.x;
    mB = fmaf(tb0.y, x0.y, mB); mB = fmaf(tb0.z, x0.z, mB);
    mB = fmaf(tb0.w, x0.w, mB); mB = fmaf(tb1.x, x1.x, mB);
    mB = fmaf(tb1.y, x1.y, mB); mB = fmaf(tb1.z, x1.z, mB);
    mB = fmaf(tb1.w, x1.w, mB); mB = fmaf(tb2.x, x2.x, mB);
    mB = fmaf(tb2.y, x2.y, mB);
    float qA = fast_exp2(mA);
    float qB = fast_exp2(mB);
    raccA = fmaf(qA, x2.z, raccA);
    raccB = fmaf(qB, x2.z, raccB);
    if (diag) {
      float2 kv = *(const float2*)(invKrow + (size_t)j * N + iA);
      traccA = fmaf(kv.x, x2.w * qA, traccA);
      traccB = fmaf(kv.y, x2.w * qB, traccB);
    }
  }
  float local = ta2.z * raccA + tb2.z * raccB;
  float local_tr = diag ? (ta2.w * traccA + tb2.w * traccB) : 0.0f;

  // ---- reduce + atomic accumulate + ticket ----
  {
    float rr = wave_reduce(local);
    if (lane == 0) redw[wv] = rr;
    if (diag) {
      float rt = wave_reduce(local_tr);
      if (lane == 0) redw[4 + wv] = rt;
    }
    __syncthreads();
    if (tid == 0) {
      float v = redw[0] + redw[1] + redw[2] + redw[3];
      atomicAdd(&ws[OFF_EDD + b * (D * D) + a * D + d], v);
      if (!diag) {
        atomicAdd(&ws[OFF_EDD + b * (D * D) + d * D + a], v);
      } else {
        atomicAdd(&ws[OFF_TR + b * D + a], redw[4] + redw[5] + redw[6] + redw[7]);
      }
      __threadfence();
      int old = atomicAdd((int*)(ws + OFF_TICKET), 1);
      s_last = (old == NQ - 1);
    }
    __syncthreads();
  }

  // ---- last block assembles the output ----
  if (s_last) {
    __threadfence();
    for (int m = tid; m < B * D; m += 256) {
      out[m] = obs_mean[m] + ws[OFF_MUD + m];
    }
    for (int cell = tid; cell < B * D * D; cell += 256) {
      int b2 = cell >> 6, ij = cell & 63;
      int i = ij >> 3, j = ij & 7;
      float edd = atomicAdd(&ws[OFF_EDD + cell], 0.0f);   // coherent read
      float mi = ws[OFF_MUD + b2 * D + i];
      float mj = ws[OFF_MUD + b2 * D + j];
      float sd = edd - mi * mj;
      if (i == j) {
        float tr = atomicAdd(&ws[OFF_TR + b2 * D + i], 0.0f);
        sd += alpha_sq[i] - tr + sigma_sq_eps[i];
      }
      float cxd = ws[OFF_V + (b2 * D + j) * E + i];   // C_xd[b,i,j] = V[b,j,i]
      float cdx = ws[OFF_V + (b2 * D + i) * E + j];
      out[B * D + cell] = obs_var[cell] + sd + cxd + cdx;
    }
  }
}

// ---------------------------------------------------------------------------
extern "C" void kernel_launch(void* const* d_in, const int* in_sizes, int n_in,
                              void* d_out, int out_size, void* d_ws, size_t ws_size,
                              hipStream_t stream) {
  const float* obs_mean     = (const float*)d_in[0];
  const float* obs_var      = (const float*)d_in[1];
  const float* action_mean  = (const float*)d_in[2];
  const float* action_var   = (const float*)d_in[3];
  const float* cross_cov    = (const float*)d_in[4];
  const float* X_train      = (const float*)d_in[5];
  const float* ell          = (const float*)d_in[6];
  const float* alpha_sq     = (const float*)d_in[7];
  const float* sigma_sq_eps = (const float*)d_in[8];
  const float* beta         = (const float*)d_in[9];
  const float* inv_K        = (const float*)d_in[10];
  float* out = (float*)d_out;
  float* ws = (float*)d_ws;

  k_prep<<<NPREP, 256, 0, stream>>>(obs_mean, obs_var, action_mean, action_var,
                                    cross_cov, X_train, ell, alpha_sq, beta, ws);
  k_q<<<NQ, 256, 0, stream>>>(obs_mean, obs_var, alpha_sq, sigma_sq_eps,
                              beta, inv_K, ws, out);
}

// Round 8
// 209.148 us; speedup vs baseline: 1.0911x; 1.0911x over previous
//
#include <hip/hip_runtime.h>
#include <math.h>

#define B 16
#define D 8
#define FDIM 2
#define N 512
#define E 10            // D + FDIM
#define NP36 36         // pairs a<=d
#define GJW (2*E)       // augmented width for Gauss-Jordan
#define NT 4            // i-tiles per (pair,b)
#define TIL 128         // i-tile size
#define NQ (NP36*B*NT)        // 2304 k_q blocks
#define NPREP (NP36*B + B*D)  // 576 pair + 128 A blocks
#define LOG2E 1.44269504088896340736f

// ---- workspace layout (float offsets) ----
#define OFF_MUD    0         // B*D          = 128
#define OFF_V      128       // B*D*E        = 1280
#define OFF_EDD    1408      // B*D*D        = 1024 (atomic-accumulated)
#define OFF_TR     2432      // B*D          = 128  (atomic-accumulated)
#define OFF_TICKET 2560      // 4
#define OFF_XNU    2564      // B*N*12       = 98304  [x0..x9,1,0] (16B-aligned)
#define OFF_W      100868    // NP36*B*100   = 57600  (log2e-folded W)
#define OFF_PA     158468    // NP36*B*N*2   = 589824 (baE, Ei) float2
#define OFF_PB     748292    // NP36*B*N*2   = 589824 (fb, cbE) float2
// total 1338116 floats = 5.35 MB

__device__ __forceinline__ void decode_pair(int p36, int* pa, int* pd) {
  int a = 0, rem = p36;
  while (rem >= D - a) { rem -= (D - a); a++; }
  *pa = a; *pd = a + rem;
}

__device__ __forceinline__ float wave_reduce(float v) {
#pragma unroll
  for (int off = 32; off > 0; off >>= 1) v += __shfl_down(v, off);
  return v;
}

__device__ __forceinline__ float fast_exp2(float x) {
#if __has_builtin(__builtin_amdgcn_exp2f)
  return __builtin_amdgcn_exp2f(x);
#else
  return exp2f(x);
#endif
}

// Single-wave Gauss-Jordan with partial pivoting on augmented E x GJW system
// in LDS. Call from ALL threads; only wave 0 acts. Caller must __syncthreads()
// after. Returns log|det(left)| on wave 0 lanes.
__device__ __forceinline__ float gj_wave(float (*M)[GJW], float* colfac,
                                         int tid) {
  float detprod = 1.0f;
  if (tid < 64) {
    int lane = tid;
    for (int k = 0; k < E; k++) {
      float v = (lane < E && lane >= k) ? fabsf(M[lane][k]) : -1.0f;
      int idx = lane;
#pragma unroll
      for (int off = 8; off > 0; off >>= 1) {
        float ov = __shfl_xor(v, off);
        int oi = __shfl_xor(idx, off);
        if (ov > v) { v = ov; idx = oi; }
      }
      int pr = __shfl(idx, 0);
      float piv = M[pr][k];
      detprod *= fabsf(piv);
      if (lane < GJW) {
        float rowp = M[pr][lane];
        float rowk = M[k][lane];
        M[pr][lane] = rowk;
        M[k][lane] = rowp / piv;
      }
      if (lane < E) colfac[lane] = M[lane][k];
      for (int i2 = lane; i2 < E * GJW; i2 += 64) {
        int r = i2 / GJW, c = i2 % GJW;
        if (r != k) M[r][c] -= colfac[r] * M[k][c];
      }
    }
  }
  return logf(detprod);
}

// ---------------------------------------------------------------------------
// k_prep: blocks [0, NP36*B): per-(pair,b) GJ -> W + PA + PB.
//         blocks [NP36*B, +B*D): mu_delta[b,d], V[b,d,:] (+XNU when d==0).
//         block 0 additionally zeroes EDD/TR/ticket.
__global__ __launch_bounds__(256) void k_prep(
    const float* __restrict__ obs_mean, const float* __restrict__ obs_var,
    const float* __restrict__ action_mean, const float* __restrict__ action_var,
    const float* __restrict__ cross_cov, const float* __restrict__ X,
    const float* __restrict__ ell, const float* __restrict__ alpha_sq,
    const float* __restrict__ beta, float* __restrict__ ws) {
  __shared__ float M[E][GJW];
  __shared__ float colfac[E];
  __shared__ float s_logdet, s_ldl;
  __shared__ float sMu[E], sSig[E * E], siLa[E], siLd[E];
  __shared__ float wred[4][11];
  __shared__ float wsh[E];

  int tid = threadIdx.x;
  int bx = blockIdx.x;

  if (bx >= NP36 * B) {
    // ===== A-path: mu_delta[b,d], V[b,d,:] =====
    int bd = bx - NP36 * B;
    int b = bd / D, d = bd % D;
    if (tid < E) {
      sMu[tid] = (tid < D) ? obs_mean[b * D + tid] : action_mean[b * FDIM + tid - D];
    }
    for (int idx = tid; idx < E * E; idx += 256) {
      int e = idx / E, f = idx % E;
      float v;
      if (e < D && f < D)      v = obs_var[(b * D + e) * D + f];
      else if (e < D)          v = cross_cov[(b * D + e) * FDIM + (f - D)];
      else if (f < D)          v = cross_cov[(b * D + f) * FDIM + (e - D)];
      else                     v = action_var[(b * FDIM + (e - D)) * FDIM + (f - D)];
      sSig[idx] = v;
    }
    __syncthreads();
    for (int idx = tid; idx < E * GJW; idx += 256) {
      int r = idx / GJW, c = idx % GJW;
      float v;
      if (c < E) {
        v = sSig[r * E + c];
        if (r == c) { float l = ell[d * E + r]; v += l * l; }
      } else {
        v = (c - E == r) ? 1.0f : 0.0f;
      }
      M[r][c] = v;
    }
    if (tid == 64) {
      float s = 0.0f;
#pragma unroll
      for (int e = 0; e < E; e++) { float l = ell[d * E + e]; s += logf(l * l); }
      s_ldl = s;
    }
    __syncthreads();
    float ld = gj_wave(M, colfac, tid);   // M[r][E+c] = Ainv
    if (tid == 0) s_logdet = ld;
    __syncthreads();
    float c0 = 0.5f * (s_ldl - s_logdet);
    float a2 = alpha_sq[d];
    float acc_mu = 0.0f, acc_w[E];
#pragma unroll
    for (int e = 0; e < E; e++) acc_w[e] = 0.0f;
    bool wx = (d == 0);
    for (int n = tid; n < N; n += 256) {
      float x[E];
#pragma unroll
      for (int e = 0; e < E; e++) x[e] = X[n * E + e] - sMu[e];
      if (wx) {
        float* xr = ws + OFF_XNU + ((size_t)b * N + n) * 12;
#pragma unroll
        for (int e = 0; e < E; e++) xr[e] = x[e];
        xr[10] = 1.0f; xr[11] = 0.0f;
      }
      float quad = 0.0f;
#pragma unroll
      for (int e = 0; e < E; e++) {
        float te = 0.0f;
#pragma unroll
        for (int f = 0; f < E; f++) te += M[e][E + f] * x[f];
        quad += x[e] * te;
      }
      float qval = a2 * __expf(c0 - 0.5f * quad);
      float bq = beta[d * N + n] * qval;
      acc_mu += bq;
#pragma unroll
      for (int e = 0; e < E; e++) acc_w[e] += bq * x[e];
    }
    int wid = tid >> 6, lane = tid & 63;
    float r = wave_reduce(acc_mu);
    if (lane == 0) wred[wid][0] = r;
#pragma unroll
    for (int e = 0; e < E; e++) {
      r = wave_reduce(acc_w[e]);
      if (lane == 0) wred[wid][e + 1] = r;
    }
    __syncthreads();
    if (tid < 11) {
      float s = wred[0][tid] + wred[1][tid] + wred[2][tid] + wred[3][tid];
      if (tid == 0) ws[OFF_MUD + b * D + d] = s;
      else wsh[tid - 1] = s;
    }
    __syncthreads();
    if (tid == 0) {
      float u[E];
#pragma unroll
      for (int f = 0; f < E; f++) {
        float s = 0.0f;
#pragma unroll
        for (int g = 0; g < E; g++) s += M[f][E + g] * wsh[g];
        u[f] = s;
      }
#pragma unroll
      for (int e = 0; e < E; e++) {
        float s = 0.0f;
#pragma unroll
        for (int f = 0; f < E; f++) s += sSig[e * E + f] * u[f];
        ws[OFF_V + (b * D + d) * E + e] = s;
      }
    }
    return;
  }

  // ===== pair path: W + PA + PB for (p36, b) =====
  if (bx == 0) {   // zero EDD(1024)+TR(128)+ticket before k_q
    for (int idx = tid; idx < 1156; idx += 256) ws[OFF_EDD + idx] = 0.0f;
  }
  int p36 = bx / B, b = bx % B;
  int a, d;
  decode_pair(p36, &a, &d);
  int pb = p36 * B + b;
  if (tid < E) {
    sMu[tid] = (tid < D) ? obs_mean[b * D + tid] : action_mean[b * FDIM + tid - D];
    float la = ell[a * E + tid]; siLa[tid] = 1.0f / (la * la);
    float ldv = ell[d * E + tid]; siLd[tid] = 1.0f / (ldv * ldv);
  }
  for (int idx = tid; idx < E * E; idx += 256) {
    int e = idx / E, f = idx % E;
    float v;
    if (e < D && f < D)      v = obs_var[(b * D + e) * D + f];
    else if (e < D)          v = cross_cov[(b * D + e) * FDIM + (f - D)];
    else if (f < D)          v = cross_cov[(b * D + f) * FDIM + (e - D)];
    else                     v = action_var[(b * FDIM + (e - D)) * FDIM + (f - D)];
    sSig[idx] = v;
  }
  __syncthreads();
  for (int idx = tid; idx < E * GJW; idx += 256) {
    int r = idx / GJW, c = idx % GJW;
    float v;
    if (c < E) v = sSig[r * E + c] * (siLa[c] + siLd[c]) + ((r == c) ? 1.0f : 0.0f);
    else       v = sSig[r * E + (c - E)];
    M[r][c] = v;
  }
  __syncthreads();
  float ld = gj_wave(M, colfac, tid);    // M[r][E+c] = S, ld = logdetR
  if (tid == 0) s_logdet = ld;
  __syncthreads();
  float ldr = s_logdet;
  float lga = logf(alpha_sq[a]);
  float lgd = logf(alpha_sq[d]);
  // W (log2e-folded)
  for (int idx = tid; idx < E * E; idx += 256) {
    int e = idx / E, f = idx % E;
    ws[OFF_W + (size_t)pb * 100 + idx] = LOG2E * siLa[e] * M[e][E + f] * siLd[f];
  }
  // PA/PB per n
  for (int n = tid; n < N; n += 256) {
    float pa[E], pd[E];
    float s2a = 0.0f, s2b = 0.0f;
#pragma unroll
    for (int e = 0; e < E; e++) {
      float xe = X[n * E + e] - sMu[e];
      pa[e] = xe * siLa[e];
      pd[e] = xe * siLd[e];
      s2a += xe * pa[e];
      s2b += xe * pd[e];
    }
    float da = 0.0f, db = 0.0f;
#pragma unroll
    for (int e = 0; e < E; e++) {
      float ta = 0.0f, td = 0.0f;
#pragma unroll
      for (int f = 0; f < E; f++) {
        float s = M[e][E + f];
        ta += s * pa[f];
        td += s * pd[f];
      }
      da += pa[e] * ta;
      db += pd[e] * td;
    }
    float ca = LOG2E * (lga - 0.5f * s2a + 0.5f * da - 0.5f * ldr);
    float cb = LOG2E * (lgd - 0.5f * s2b + 0.5f * db);
    float Ei = fast_exp2(ca);
    float cbE = fast_exp2(cb);
    ((float2*)(ws + OFF_PA))[(size_t)pb * N + n] =
        make_float2(beta[(size_t)a * N + n] * Ei, Ei);
    ((float2*)(ws + OFF_PB))[(size_t)pb * N + n] =
        make_float2(beta[(size_t)d * N + n] * cbE, cbE);
  }
}

// ---------------------------------------------------------------------------
// k_q: per (pair, b, i-tile). Lane holds 4 j-rows in registers; T-rows are
// wave-uniform LDS broadcasts amortized over 4 j (18:1 VALU:LDS ratio).
// wave: ihalf = w>>1 (64 rows), jhalf = w&1 (lane*4 within 256 j).
// Last block (ticket) assembles the final output.
__global__ __launch_bounds__(256, 2) void k_q(
    const float* __restrict__ obs_mean, const float* __restrict__ obs_var,
    const float* __restrict__ alpha_sq, const float* __restrict__ sigma_sq_eps,
    const float* __restrict__ invK, float* __restrict__ ws,
    float* __restrict__ out) {
  __shared__ float sxj[N * 12];      // 24576 B: [x0..x9, fb, cbE] per j
  __shared__ float sT[TIL * 12];     // 6144 B:  [t0..t9, baE, Ei] per i-row
  __shared__ float sW[100];
  __shared__ float redw[8];
  __shared__ int s_last;

  int tid = threadIdx.x;
  int bx = blockIdx.x;
  int tile = bx & (NT - 1);
  int rest = bx >> 2;
  int b = rest & (B - 1);
  int p36 = rest >> 4;
  int a, d;
  decode_pair(p36, &a, &d);
  int pb = p36 * B + b;
  bool diag = (a == d);
  int i0 = tile * TIL;

  // ---- phase A0: load W ----
  if (tid < 100) sW[tid] = ws[OFF_W + (size_t)pb * 100 + tid];

  // ---- phase A1: build sxj rows [x, fb, cbE] for all 512 j ----
  for (int j = tid; j < N; j += 256) {
    const float4* xp = (const float4*)(ws + OFF_XNU + ((size_t)b * N + j) * 12);
    float4 a0 = xp[0], a1 = xp[1], a2 = xp[2];
    float2 pbv = ((const float2*)(ws + OFF_PB))[(size_t)pb * N + j];
    float4* s4 = (float4*)(sxj + j * 12);
    s4[0] = a0;
    s4[1] = a1;
    s4[2] = make_float4(a2.x, a2.y, pbv.x, pbv.y);
  }
  __syncthreads();

  // ---- phase B: build sT rows [t, baE, Ei] for own 128 i ----
  for (int idx = tid; idx < TIL * E; idx += 256) {
    int il = idx / E, f = idx % E;
    const float* x = sxj + (i0 + il) * 12;
    float acc = 0.0f;
#pragma unroll
    for (int e = 0; e < E; e++) acc += x[e] * sW[e * 10 + f];
    sT[il * 12 + f] = acc;
  }
  if (tid < TIL) {
    float2 pav = ((const float2*)(ws + OFF_PA))[(size_t)pb * N + i0 + tid];
    sT[tid * 12 + 10] = pav.x;    // baE
    sT[tid * 12 + 11] = pav.y;    // Ei
  }
  __syncthreads();

  // ---- load per-lane j fragment (4 consecutive j) into registers ----
  int lane = tid & 63;
  int w = tid >> 6;
  int ihalf = w >> 1;
  int jhalf = w & 1;
  int j0 = jhalf * 256 + lane * 4;
  float xj[4][10], fbv[4], cbEv[4];
#pragma unroll
  for (int k = 0; k < 4; k++) {
    const float4* s4 = (const float4*)(sxj + (j0 + k) * 12);
    float4 a0 = s4[0], a1 = s4[1], a2 = s4[2];
    xj[k][0] = a0.x; xj[k][1] = a0.y; xj[k][2] = a0.z; xj[k][3] = a0.w;
    xj[k][4] = a1.x; xj[k][5] = a1.y; xj[k][6] = a1.z; xj[k][7] = a1.w;
    xj[k][8] = a2.x; xj[k][9] = a2.y;
    fbv[k] = a2.z; cbEv[k] = a2.w;
  }
  float acc[4] = {0.0f, 0.0f, 0.0f, 0.0f};
  float acctr[4] = {0.0f, 0.0f, 0.0f, 0.0f};

  // ---- main loop: 64 rows, T-row broadcast from LDS ----
  const float* invKa = invK + (size_t)a * N * N;
  int rbase = ihalf * 64;
#pragma unroll 4
  for (int il = 0; il < 64; il++) {
    int row = rbase + il;
    const float4* tp = (const float4*)&sT[row * 12];
    float4 t0 = tp[0], t1 = tp[1], t2 = tp[2];
    float baE = t2.z, Ei = t2.w;
    float kr[4];
    if (diag) {
      float4 kv = *(const float4*)(invKa + (size_t)(i0 + row) * N + j0);
      kr[0] = kv.x; kr[1] = kv.y; kr[2] = kv.z; kr[3] = kv.w;
    }
#pragma unroll
    for (int k = 0; k < 4; k++) {
      float m = t0.x * xj[k][0];
      m = fmaf(t0.y, xj[k][1], m);
      m = fmaf(t0.z, xj[k][2], m);
      m = fmaf(t0.w, xj[k][3], m);
      m = fmaf(t1.x, xj[k][4], m);
      m = fmaf(t1.y, xj[k][5], m);
      m = fmaf(t1.z, xj[k][6], m);
      m = fmaf(t1.w, xj[k][7], m);
      m = fmaf(t2.x, xj[k][8], m);
      m = fmaf(t2.y, xj[k][9], m);
      float q = fast_exp2(m);
      acc[k] = fmaf(baE, q, acc[k]);
      if (diag) acctr[k] = fmaf(kr[k], Ei * q, acctr[k]);
    }
  }

  // ---- fold per-j factors, reduce, atomic accumulate, ticket ----
  float local = fbv[0] * acc[0] + fbv[1] * acc[1] +
                fbv[2] * acc[2] + fbv[3] * acc[3];
  float local_tr = diag ? (cbEv[0] * acctr[0] + cbEv[1] * acctr[1] +
                           cbEv[2] * acctr[2] + cbEv[3] * acctr[3]) : 0.0f;
  {
    float rr = wave_reduce(local);
    if (lane == 0) redw[w] = rr;
    if (diag) {
      float rt = wave_reduce(local_tr);
      if (lane == 0) redw[4 + w] = rt;
    }
    __syncthreads();
    if (tid == 0) {
      float v = redw[0] + redw[1] + redw[2] + redw[3];
      atomicAdd(&ws[OFF_EDD + b * (D * D) + a * D + d], v);
      if (!diag) {
        atomicAdd(&ws[OFF_EDD + b * (D * D) + d * D + a], v);
      } else {
        atomicAdd(&ws[OFF_TR + b * D + a], redw[4] + redw[5] + redw[6] + redw[7]);
      }
      __threadfence();
      int old = atomicAdd((int*)(ws + OFF_TICKET), 1);
      s_last = (old == NQ - 1);
    }
    __syncthreads();
  }

  // ---- last block assembles the output ----
  if (s_last) {
    __threadfence();
    for (int m = tid; m < B * D; m += 256) {
      out[m] = obs_mean[m] + ws[OFF_MUD + m];
    }
    for (int cell = tid; cell < B * D * D; cell += 256) {
      int b2 = cell >> 6, ij = cell & 63;
      int i = ij >> 3, j = ij & 7;
      float edd = atomicAdd(&ws[OFF_EDD + cell], 0.0f);   // coherent read
      float mi = ws[OFF_MUD + b2 * D + i];
      float mj = ws[OFF_MUD + b2 * D + j];
      float sd = edd - mi * mj;
      if (i == j) {
        float tr = atomicAdd(&ws[OFF_TR + b2 * D + i], 0.0f);
        sd += alpha_sq[i] - tr + sigma_sq_eps[i];
      }
      float cxd = ws[OFF_V + (b2 * D + j) * E + i];   // C_xd[b,i,j] = V[b,j,i]
      float cdx = ws[OFF_V + (b2 * D + i) * E + j];
      out[B * D + cell] = obs_var[cell] + sd + cxd + cdx;
    }
  }
}

// ---------------------------------------------------------------------------
extern "C" void kernel_launch(void* const* d_in, const int* in_sizes, int n_in,
                              void* d_out, int out_size, void* d_ws, size_t ws_size,
                              hipStream_t stream) {
  const float* obs_mean     = (const float*)d_in[0];
  const float* obs_var      = (const float*)d_in[1];
  const float* action_mean  = (const float*)d_in[2];
  const float* action_var   = (const float*)d_in[3];
  const float* cross_cov    = (const float*)d_in[4];
  const float* X_train      = (const float*)d_in[5];
  const float* ell          = (const float*)d_in[6];
  const float* alpha_sq     = (const float*)d_in[7];
  const float* sigma_sq_eps = (const float*)d_in[8];
  const float* beta         = (const float*)d_in[9];
  const float* inv_K        = (const float*)d_in[10];
  float* out = (float*)d_out;
  float* ws = (float*)d_ws;

  k_prep<<<NPREP, 256, 0, stream>>>(obs_mean, obs_var, action_mean, action_var,
                                    cross_cov, X_train, ell, alpha_sq, beta, ws);
  k_q<<<NQ, 256, 0, stream>>>(obs_mean, obs_var, alpha_sq, sigma_sq_eps,
                              inv_K, ws, out);
}

// Round 9
// 202.916 us; speedup vs baseline: 1.1246x; 1.0307x over previous
//
#include <hip/hip_runtime.h>
#include <math.h>

#define B 16
#define D 8
#define FDIM 2
#define N 512
#define E 10            // D + FDIM
#define NP36 36         // pairs a<=d
#define GJW (2*E)       // augmented width for Gauss-Jordan
#define NT 4            // i-tiles per (pair,b)
#define TIL 128         // i-tile size
#define NQ (NP36*B*NT)        // 2304 k_q blocks
#define NPREP (NP36*B + B*D)  // 576 pair + 128 A blocks
#define LOG2E 1.44269504088896340736f

// ---- workspace layout (float offsets) ----
#define OFF_MUD    0         // B*D          = 128
#define OFF_V      128       // B*D*E        = 1280
#define OFF_EDD    1408      // B*D*D        = 1024 (atomic-accumulated)
#define OFF_TR     2432      // B*D          = 128  (atomic-accumulated)
#define OFF_TICKET 2560      // 4
#define OFF_XNU    2564      // B*N*12       = 98304  [x0..x9,1,0] (16B-aligned)
#define OFF_W      100868    // NP36*B*100   = 57600  (log2e-folded W)
#define OFF_PA     158468    // NP36*B*N*2   = 589824 (baE, Ei) float2
#define OFF_PB     748292    // NP36*B*N*2   = 589824 (fb, cbE) float2
// total 1338116 floats = 5.35 MB

__device__ __forceinline__ void decode_pair(int p36, int* pa, int* pd) {
  int a = 0, rem = p36;
  while (rem >= D - a) { rem -= (D - a); a++; }
  *pa = a; *pd = a + rem;
}

__device__ __forceinline__ float wave_reduce(float v) {
#pragma unroll
  for (int off = 32; off > 0; off >>= 1) v += __shfl_down(v, off);
  return v;
}

__device__ __forceinline__ float fast_exp2(float x) {
#if __has_builtin(__builtin_amdgcn_exp2f)
  return __builtin_amdgcn_exp2f(x);
#else
  return exp2f(x);
#endif
}

// Block-parallel Gauss-Jordan with partial pivoting on augmented E x GJW
// system in LDS (256 threads, barriers). On exit right half = left^{-1} *
// original-right; *s_det = |det(left)| (product of pivots).
__device__ __forceinline__ void gj_block(float (*M)[GJW], float* pivrow,
                                         float* colfac, int* s_piv,
                                         float* s_det, int tid) {
  if (tid == 0) *s_det = 1.0f;
  __syncthreads();
  for (int k = 0; k < E; k++) {
    if (tid == 0) {
      int pr = k; float best = fabsf(M[k][k]);
      for (int r = k + 1; r < E; r++) {
        float v = fabsf(M[r][k]);
        if (v > best) { best = v; pr = r; }
      }
      *s_piv = pr;
      *s_det *= fabsf(M[pr][k]);
    }
    __syncthreads();
    int pr = *s_piv;
    if (tid < GJW) {               // wave-0 lanes, loads precede stores
      int c = tid;
      float piv = M[pr][k];
      float rowp = M[pr][c];
      float rowk = M[k][c];
      float pw = rowp / piv;
      pivrow[c] = pw;
      M[pr][c] = rowk;
      M[k][c] = pw;
    }
    __syncthreads();
    if (tid < E) colfac[tid] = M[tid][k];
    __syncthreads();
    for (int idx = tid; idx < E * GJW; idx += 256) {
      int r = idx / GJW, c = idx % GJW;
      if (r != k) M[r][c] -= colfac[r] * pivrow[c];
    }
    __syncthreads();
  }
}

// ---------------------------------------------------------------------------
// k_prep: blocks [0, NP36*B): per-(pair,b) GJ -> W + PA + PB.
//         blocks [NP36*B, +B*D): mu_delta[b,d], V[b,d,:] (+XNU when d==0).
//         block 0 additionally zeroes EDD/TR/ticket.
__global__ __launch_bounds__(256) void k_prep(
    const float* __restrict__ obs_mean, const float* __restrict__ obs_var,
    const float* __restrict__ action_mean, const float* __restrict__ action_var,
    const float* __restrict__ cross_cov, const float* __restrict__ X,
    const float* __restrict__ ell, const float* __restrict__ alpha_sq,
    const float* __restrict__ beta, float* __restrict__ ws) {
  __shared__ float M[E][GJW];
  __shared__ float pivrow[GJW];
  __shared__ float colfac[E];
  __shared__ int   s_piv;
  __shared__ float s_det;
  __shared__ float sMu[E], sSig[E * E], siLa[E], siLd[E];
  __shared__ float wred[4][11];
  __shared__ float wsh[E];

  int tid = threadIdx.x;
  int bx = blockIdx.x;

  if (bx >= NP36 * B) {
    // ===== A-path: mu_delta[b,d], V[b,d,:] =====
    int bd = bx - NP36 * B;
    int b = bd / D, d = bd % D;
    if (tid < E) {
      sMu[tid] = (tid < D) ? obs_mean[b * D + tid] : action_mean[b * FDIM + tid - D];
    }
    for (int idx = tid; idx < E * E; idx += 256) {
      int e = idx / E, f = idx % E;
      float v;
      if (e < D && f < D)      v = obs_var[(b * D + e) * D + f];
      else if (e < D)          v = cross_cov[(b * D + e) * FDIM + (f - D)];
      else if (f < D)          v = cross_cov[(b * D + f) * FDIM + (e - D)];
      else                     v = action_var[(b * FDIM + (e - D)) * FDIM + (f - D)];
      sSig[idx] = v;
    }
    __syncthreads();
    for (int idx = tid; idx < E * GJW; idx += 256) {
      int r = idx / GJW, c = idx % GJW;
      float v;
      if (c < E) {
        v = sSig[r * E + c];
        if (r == c) { float l = ell[d * E + r]; v += l * l; }
      } else {
        v = (c - E == r) ? 1.0f : 0.0f;
      }
      M[r][c] = v;
    }
    __syncthreads();
    gj_block(M, pivrow, colfac, &s_piv, &s_det, tid);  // M[r][E+c] = Ainv
    float logdetLam = 0.0f;
#pragma unroll
    for (int e = 0; e < E; e++) { float l = ell[d * E + e]; logdetLam += logf(l * l); }
    float c0 = 0.5f * (logdetLam - logf(s_det));
    float a2 = alpha_sq[d];
    float acc_mu = 0.0f, acc_w[E];
#pragma unroll
    for (int e = 0; e < E; e++) acc_w[e] = 0.0f;
    bool wx = (d == 0);
    for (int n = tid; n < N; n += 256) {
      float x[E];
#pragma unroll
      for (int e = 0; e < E; e++) x[e] = X[n * E + e] - sMu[e];
      if (wx) {
        float* xr = ws + OFF_XNU + ((size_t)b * N + n) * 12;
#pragma unroll
        for (int e = 0; e < E; e++) xr[e] = x[e];
        xr[10] = 1.0f; xr[11] = 0.0f;
      }
      float quad = 0.0f;
#pragma unroll
      for (int e = 0; e < E; e++) {
        float te = 0.0f;
#pragma unroll
        for (int f = 0; f < E; f++) te += M[e][E + f] * x[f];
        quad += x[e] * te;
      }
      float qval = a2 * __expf(c0 - 0.5f * quad);
      float bq = beta[d * N + n] * qval;
      acc_mu += bq;
#pragma unroll
      for (int e = 0; e < E; e++) acc_w[e] += bq * x[e];
    }
    int wid = tid >> 6, lane = tid & 63;
    float r = wave_reduce(acc_mu);
    if (lane == 0) wred[wid][0] = r;
#pragma unroll
    for (int e = 0; e < E; e++) {
      r = wave_reduce(acc_w[e]);
      if (lane == 0) wred[wid][e + 1] = r;
    }
    __syncthreads();
    if (tid < 11) {
      float s = wred[0][tid] + wred[1][tid] + wred[2][tid] + wred[3][tid];
      if (tid == 0) ws[OFF_MUD + b * D + d] = s;
      else wsh[tid - 1] = s;
    }
    __syncthreads();
    if (tid == 0) {
      float u[E];
#pragma unroll
      for (int f = 0; f < E; f++) {
        float s = 0.0f;
#pragma unroll
        for (int g = 0; g < E; g++) s += M[f][E + g] * wsh[g];
        u[f] = s;
      }
#pragma unroll
      for (int e = 0; e < E; e++) {
        float s = 0.0f;
#pragma unroll
        for (int f = 0; f < E; f++) s += sSig[e * E + f] * u[f];
        ws[OFF_V + (b * D + d) * E + e] = s;
      }
    }
    return;
  }

  // ===== pair path: W + PA + PB for (p36, b) =====
  if (bx == 0) {   // zero EDD(1024)+TR(128)+ticket before k_q
    for (int idx = tid; idx < 1156; idx += 256) ws[OFF_EDD + idx] = 0.0f;
  }
  int p36 = bx / B, b = bx % B;
  int a, d;
  decode_pair(p36, &a, &d);
  int pb = p36 * B + b;
  if (tid < E) {
    sMu[tid] = (tid < D) ? obs_mean[b * D + tid] : action_mean[b * FDIM + tid - D];
    float la = ell[a * E + tid]; siLa[tid] = 1.0f / (la * la);
    float ldv = ell[d * E + tid]; siLd[tid] = 1.0f / (ldv * ldv);
  }
  for (int idx = tid; idx < E * E; idx += 256) {
    int e = idx / E, f = idx % E;
    float v;
    if (e < D && f < D)      v = obs_var[(b * D + e) * D + f];
    else if (e < D)          v = cross_cov[(b * D + e) * FDIM + (f - D)];
    else if (f < D)          v = cross_cov[(b * D + f) * FDIM + (e - D)];
    else                     v = action_var[(b * FDIM + (e - D)) * FDIM + (f - D)];
    sSig[idx] = v;
  }
  __syncthreads();
  for (int idx = tid; idx < E * GJW; idx += 256) {
    int r = idx / GJW, c = idx % GJW;
    float v;
    if (c < E) v = sSig[r * E + c] * (siLa[c] + siLd[c]) + ((r == c) ? 1.0f : 0.0f);
    else       v = sSig[r * E + (c - E)];
    M[r][c] = v;
  }
  __syncthreads();
  gj_block(M, pivrow, colfac, &s_piv, &s_det, tid);   // M[r][E+c] = S
  float ldr = logf(s_det);
  float lga = logf(alpha_sq[a]);
  float lgd = logf(alpha_sq[d]);
  // W (log2e-folded)
  for (int idx = tid; idx < E * E; idx += 256) {
    int e = idx / E, f = idx % E;
    ws[OFF_W + (size_t)pb * 100 + idx] = LOG2E * siLa[e] * M[e][E + f] * siLd[f];
  }
  // PA/PB per n
  for (int n = tid; n < N; n += 256) {
    float pa[E], pd[E];
    float s2a = 0.0f, s2b = 0.0f;
#pragma unroll
    for (int e = 0; e < E; e++) {
      float xe = X[n * E + e] - sMu[e];
      pa[e] = xe * siLa[e];
      pd[e] = xe * siLd[e];
      s2a += xe * pa[e];
      s2b += xe * pd[e];
    }
    float da = 0.0f, db = 0.0f;
#pragma unroll
    for (int e = 0; e < E; e++) {
      float ta = 0.0f, td = 0.0f;
#pragma unroll
      for (int f = 0; f < E; f++) {
        float s = M[e][E + f];
        ta += s * pa[f];
        td += s * pd[f];
      }
      da += pa[e] * ta;
      db += pd[e] * td;
    }
    float ca = LOG2E * (lga - 0.5f * s2a + 0.5f * da - 0.5f * ldr);
    float cb = LOG2E * (lgd - 0.5f * s2b + 0.5f * db);
    float Ei = fast_exp2(ca);
    float cbE = fast_exp2(cb);
    ((float2*)(ws + OFF_PA))[(size_t)pb * N + n] =
        make_float2(beta[(size_t)a * N + n] * Ei, Ei);
    ((float2*)(ws + OFF_PB))[(size_t)pb * N + n] =
        make_float2(beta[(size_t)d * N + n] * cbE, cbE);
  }
}

// 10-term dot of a T-row (t0,t1,t2) against a j-fragment (xa,xb,xc)
#define DOT10(t0, t1, t2, xa, xb, xc)                                          \
  fmaf(t2.y, xc.y,                                                             \
  fmaf(t2.x, xc.x,                                                             \
  fmaf(t1.w, xb.w,                                                             \
  fmaf(t1.z, xb.z,                                                             \
  fmaf(t1.y, xb.y,                                                             \
  fmaf(t1.x, xb.x,                                                             \
  fmaf(t0.w, xa.w,                                                             \
  fmaf(t0.z, xa.z,                                                             \
  fmaf(t0.y, xa.y, t0.x * xa.x)))))))))

// ---------------------------------------------------------------------------
// k_q: per (pair, b, i-tile). Lane holds 4 j-fragments as NAMED float4s
// (loaded once from global XNU, L2-hot); T-rows are wave-uniform LDS
// broadcasts amortized over 4 j. No sxj LDS array -> ~7 KB LDS.
// Last block (ticket) assembles the final output.
__global__ __launch_bounds__(256) void k_q(
    const float* __restrict__ obs_mean, const float* __restrict__ obs_var,
    const float* __restrict__ alpha_sq, const float* __restrict__ sigma_sq_eps,
    const float* __restrict__ invK, float* __restrict__ ws,
    float* __restrict__ out) {
  __shared__ float sT[TIL * 12];     // 6144 B: [t0..t9, baE, Ei] per i-row
  __shared__ float sW[100];
  __shared__ float redw[8];
  __shared__ int s_last;

  int tid = threadIdx.x;
  int bx = blockIdx.x;
  int tile = bx & (NT - 1);
  int rest = bx >> 2;
  int b = rest & (B - 1);
  int p36 = rest >> 4;
  int a, d;
  decode_pair(p36, &a, &d);
  int pb = p36 * B + b;
  bool diag = (a == d);
  int i0 = tile * TIL;

  // ---- load W into LDS ----
  if (tid < 100) sW[tid] = ws[OFF_W + (size_t)pb * 100 + tid];

  // ---- per-lane j fragments: 4 consecutive j from global XNU (named) ----
  int lane = tid & 63;
  int w = tid >> 6;
  int ihalf = w >> 1;
  int jhalf = w & 1;
  int j0 = jhalf * 256 + lane * 4;
  const float4* xp = (const float4*)(ws + OFF_XNU + ((size_t)b * N + j0) * 12);
  float4 xA0 = xp[0], xA1 = xp[1], xA2 = xp[2];
  float4 xB0 = xp[3], xB1 = xp[4], xB2 = xp[5];
  float4 xC0 = xp[6], xC1 = xp[7], xC2 = xp[8];
  float4 xD0 = xp[9], xD1 = xp[10], xD2 = xp[11];
  const float2* pbp = ((const float2*)(ws + OFF_PB)) + (size_t)pb * N + j0;
  float2 pb0 = pbp[0], pb1 = pbp[1], pb2 = pbp[2], pb3 = pbp[3];
  __syncthreads();

  // ---- build sT rows [t, baE, Ei] for own 128 i (threads 0..127) ----
  if (tid < TIL) {
    const float4* xip = (const float4*)(ws + OFF_XNU + ((size_t)b * N + i0 + tid) * 12);
    float4 a0 = xip[0], a1 = xip[1], a2 = xip[2];
    float x[10] = {a0.x, a0.y, a0.z, a0.w, a1.x, a1.y, a1.z, a1.w, a2.x, a2.y};
#pragma unroll
    for (int f = 0; f < E; f++) {
      float acc = 0.0f;
#pragma unroll
      for (int e = 0; e < E; e++) acc += x[e] * sW[e * 10 + f];
      sT[tid * 12 + f] = acc;
    }
    float2 pav = ((const float2*)(ws + OFF_PA))[(size_t)pb * N + i0 + tid];
    sT[tid * 12 + 10] = pav.x;    // baE
    sT[tid * 12 + 11] = pav.y;    // Ei
  }
  __syncthreads();

  // ---- main loop: 64 rows per wave, T-row broadcast from LDS ----
  float accA = 0.0f, accB = 0.0f, accC = 0.0f, accD = 0.0f;
  float trA = 0.0f, trB = 0.0f, trC = 0.0f, trD = 0.0f;
  const float* invKa = invK + (size_t)a * N * N;
  int rbase = ihalf * 64;
#pragma unroll 4
  for (int il = 0; il < 64; il++) {
    int row = rbase + il;
    const float4* tp = (const float4*)&sT[row * 12];
    float4 t0 = tp[0], t1 = tp[1], t2 = tp[2];
    float baE = t2.z, Ei = t2.w;
    float4 kv;
    if (diag) kv = *(const float4*)(invKa + (size_t)(i0 + row) * N + j0);
    float mA = DOT10(t0, t1, t2, xA0, xA1, xA2);
    float mB = DOT10(t0, t1, t2, xB0, xB1, xB2);
    float mC = DOT10(t0, t1, t2, xC0, xC1, xC2);
    float mD = DOT10(t0, t1, t2, xD0, xD1, xD2);
    float qA = fast_exp2(mA);
    float qB = fast_exp2(mB);
    float qC = fast_exp2(mC);
    float qD = fast_exp2(mD);
    accA = fmaf(baE, qA, accA);
    accB = fmaf(baE, qB, accB);
    accC = fmaf(baE, qC, accC);
    accD = fmaf(baE, qD, accD);
    if (diag) {
      trA = fmaf(kv.x, Ei * qA, trA);
      trB = fmaf(kv.y, Ei * qB, trB);
      trC = fmaf(kv.z, Ei * qC, trC);
      trD = fmaf(kv.w, Ei * qD, trD);
    }
  }

  // ---- fold per-j factors, reduce, atomic accumulate, ticket ----
  float local = pb0.x * accA + pb1.x * accB + pb2.x * accC + pb3.x * accD;
  float local_tr = diag ? (pb0.y * trA + pb1.y * trB + pb2.y * trC + pb3.y * trD)
                        : 0.0f;
  {
    float rr = wave_reduce(local);
    if (lane == 0) redw[w] = rr;
    if (diag) {
      float rt = wave_reduce(local_tr);
      if (lane == 0) redw[4 + w] = rt;
    }
    __syncthreads();
    if (tid == 0) {
      float v = redw[0] + redw[1] + redw[2] + redw[3];
      atomicAdd(&ws[OFF_EDD + b * (D * D) + a * D + d], v);
      if (!diag) {
        atomicAdd(&ws[OFF_EDD + b * (D * D) + d * D + a], v);
      } else {
        atomicAdd(&ws[OFF_TR + b * D + a], redw[4] + redw[5] + redw[6] + redw[7]);
      }
      __threadfence();
      int old = atomicAdd((int*)(ws + OFF_TICKET), 1);
      s_last = (old == NQ - 1);
    }
    __syncthreads();
  }

  // ---- last block assembles the output ----
  if (s_last) {
    __threadfence();
    for (int m = tid; m < B * D; m += 256) {
      out[m] = obs_mean[m] + ws[OFF_MUD + m];
    }
    for (int cell = tid; cell < B * D * D; cell += 256) {
      int b2 = cell >> 6, ij = cell & 63;
      int i = ij >> 3, j = ij & 7;
      float edd = atomicAdd(&ws[OFF_EDD + cell], 0.0f);   // coherent read
      float mi = ws[OFF_MUD + b2 * D + i];
      float mj = ws[OFF_MUD + b2 * D + j];
      float sd = edd - mi * mj;
      if (i == j) {
        float tr = atomicAdd(&ws[OFF_TR + b2 * D + i], 0.0f);
        sd += alpha_sq[i] - tr + sigma_sq_eps[i];
      }
      float cxd = ws[OFF_V + (b2 * D + j) * E + i];   // C_xd[b,i,j] = V[b,j,i]
      float cdx = ws[OFF_V + (b2 * D + i) * E + j];
      out[B * D + cell] = obs_var[cell] + sd + cxd + cdx;
    }
  }
}

// ---------------------------------------------------------------------------
extern "C" void kernel_launch(void* const* d_in, const int* in_sizes, int n_in,
                              void* d_out, int out_size, void* d_ws, size_t ws_size,
                              hipStream_t stream) {
  const float* obs_mean     = (const float*)d_in[0];
  const float* obs_var      = (const float*)d_in[1];
  const float* action_mean  = (const float*)d_in[2];
  const float* action_var   = (const float*)d_in[3];
  const float* cross_cov    = (const float*)d_in[4];
  const float* X_train      = (const float*)d_in[5];
  const float* ell          = (const float*)d_in[6];
  const float* alpha_sq     = (const float*)d_in[7];
  const float* sigma_sq_eps = (const float*)d_in[8];
  const float* beta         = (const float*)d_in[9];
  const float* inv_K        = (const float*)d_in[10];
  float* out = (float*)d_out;
  float* ws = (float*)d_ws;

  k_prep<<<NPREP, 256, 0, stream>>>(obs_mean, obs_var, action_mean, action_var,
                                    cross_cov, X_train, ell, alpha_sq, beta, ws);
  k_q<<<NQ, 256, 0, stream>>>(obs_mean, obs_var, alpha_sq, sigma_sq_eps,
                              inv_K, ws, out);
}

// Round 10
// 195.452 us; speedup vs baseline: 1.1676x; 1.0382x over previous
//
#include <hip/hip_runtime.h>
#include <math.h>

#define B 16
#define D 8
#define FDIM 2
#define N 512
#define E 10            // D + FDIM
#define NP36 36         // pairs a<=d
#define GJW (2*E)       // augmented width for Gauss-Jordan
#define NT 4            // i-tiles per (pair,b)
#define TIL 128         // i-tile size
#define NQ (NP36*B*NT)        // 2304 k_q blocks
#define NPREP (NP36*B + B*D)  // 576 pair + 128 A blocks
#define LOG2E 1.44269504088896340736f

// ---- workspace layout (float offsets) ----
#define OFF_MUD    0         // B*D          = 128
#define OFF_V      128       // B*D*E        = 1280
#define OFF_EDD    1408      // B*D*D        = 1024 (atomic-accumulated)
#define OFF_TR     2432      // B*D          = 128  (atomic-accumulated)
#define OFF_TICKET 2560      // 4
#define OFF_XNU    2564      // B*N*12       = 98304  [x0..x9,1,0] (16B-aligned)
#define OFF_W      100868    // NP36*B*100   = 57600  (log2e-folded W)
#define OFF_PA     158468    // NP36*B*N*2   = 589824 (baE, Ei) float2
#define OFF_PB     748292    // NP36*B*N*2   = 589824 (fb, cbE) float2
// total 1338116 floats = 5.35 MB

__device__ __forceinline__ void decode_pair(int p36, int* pa, int* pd) {
  int a = 0, rem = p36;
  while (rem >= D - a) { rem -= (D - a); a++; }
  *pa = a; *pd = a + rem;
}

__device__ __forceinline__ float wave_reduce(float v) {
#pragma unroll
  for (int off = 32; off > 0; off >>= 1) v += __shfl_down(v, off);
  return v;
}

__device__ __forceinline__ float fast_exp2(float x) {
#if __has_builtin(__builtin_amdgcn_exp2f)
  return __builtin_amdgcn_exp2f(x);
#else
  return exp2f(x);
#endif
}

// Block-parallel Gauss-Jordan with partial pivoting on augmented E x GJW
// system in LDS (256 threads, barriers). On exit right half = left^{-1} *
// original-right; *s_det = |det(left)| (product of pivots).
__device__ __forceinline__ void gj_block(float (*M)[GJW], float* pivrow,
                                         float* colfac, int* s_piv,
                                         float* s_det, int tid) {
  if (tid == 0) *s_det = 1.0f;
  __syncthreads();
  for (int k = 0; k < E; k++) {
    if (tid == 0) {
      int pr = k; float best = fabsf(M[k][k]);
      for (int r = k + 1; r < E; r++) {
        float v = fabsf(M[r][k]);
        if (v > best) { best = v; pr = r; }
      }
      *s_piv = pr;
      *s_det *= fabsf(M[pr][k]);
    }
    __syncthreads();
    int pr = *s_piv;
    if (tid < GJW) {               // wave-0 lanes, loads precede stores
      int c = tid;
      float piv = M[pr][k];
      float rowp = M[pr][c];
      float rowk = M[k][c];
      float pw = rowp / piv;
      pivrow[c] = pw;
      M[pr][c] = rowk;
      M[k][c] = pw;
    }
    __syncthreads();
    if (tid < E) colfac[tid] = M[tid][k];
    __syncthreads();
    for (int idx = tid; idx < E * GJW; idx += 256) {
      int r = idx / GJW, c = idx % GJW;
      if (r != k) M[r][c] -= colfac[r] * pivrow[c];
    }
    __syncthreads();
  }
}

// ---------------------------------------------------------------------------
// k_prep: blocks [0, NP36*B): per-(pair,b) GJ -> W + PA + PB.
//         blocks [NP36*B, +B*D): mu_delta[b,d], V[b,d,:] (+XNU when d==0).
//         block 0 additionally zeroes EDD/TR/ticket.
__global__ __launch_bounds__(256) void k_prep(
    const float* __restrict__ obs_mean, const float* __restrict__ obs_var,
    const float* __restrict__ action_mean, const float* __restrict__ action_var,
    const float* __restrict__ cross_cov, const float* __restrict__ X,
    const float* __restrict__ ell, const float* __restrict__ alpha_sq,
    const float* __restrict__ beta, float* __restrict__ ws) {
  __shared__ float M[E][GJW];
  __shared__ float pivrow[GJW];
  __shared__ float colfac[E];
  __shared__ int   s_piv;
  __shared__ float s_det;
  __shared__ float sMu[E], sSig[E * E], siLa[E], siLd[E];
  __shared__ float wred[4][11];
  __shared__ float wsh[E];

  int tid = threadIdx.x;
  int bx = blockIdx.x;

  if (bx >= NP36 * B) {
    // ===== A-path: mu_delta[b,d], V[b,d,:] =====
    int bd = bx - NP36 * B;
    int b = bd / D, d = bd % D;
    if (tid < E) {
      sMu[tid] = (tid < D) ? obs_mean[b * D + tid] : action_mean[b * FDIM + tid - D];
    }
    for (int idx = tid; idx < E * E; idx += 256) {
      int e = idx / E, f = idx % E;
      float v;
      if (e < D && f < D)      v = obs_var[(b * D + e) * D + f];
      else if (e < D)          v = cross_cov[(b * D + e) * FDIM + (f - D)];
      else if (f < D)          v = cross_cov[(b * D + f) * FDIM + (e - D)];
      else                     v = action_var[(b * FDIM + (e - D)) * FDIM + (f - D)];
      sSig[idx] = v;
    }
    __syncthreads();
    for (int idx = tid; idx < E * GJW; idx += 256) {
      int r = idx / GJW, c = idx % GJW;
      float v;
      if (c < E) {
        v = sSig[r * E + c];
        if (r == c) { float l = ell[d * E + r]; v += l * l; }
      } else {
        v = (c - E == r) ? 1.0f : 0.0f;
      }
      M[r][c] = v;
    }
    __syncthreads();
    gj_block(M, pivrow, colfac, &s_piv, &s_det, tid);  // M[r][E+c] = Ainv
    float logdetLam = 0.0f;
#pragma unroll
    for (int e = 0; e < E; e++) { float l = ell[d * E + e]; logdetLam += logf(l * l); }
    float c0 = 0.5f * (logdetLam - logf(s_det));
    float a2 = alpha_sq[d];
    float acc_mu = 0.0f, acc_w[E];
#pragma unroll
    for (int e = 0; e < E; e++) acc_w[e] = 0.0f;
    bool wx = (d == 0);
    for (int n = tid; n < N; n += 256) {
      float x[E];
#pragma unroll
      for (int e = 0; e < E; e++) x[e] = X[n * E + e] - sMu[e];
      if (wx) {
        float* xr = ws + OFF_XNU + ((size_t)b * N + n) * 12;
#pragma unroll
        for (int e = 0; e < E; e++) xr[e] = x[e];
        xr[10] = 1.0f; xr[11] = 0.0f;
      }
      float quad = 0.0f;
#pragma unroll
      for (int e = 0; e < E; e++) {
        float te = 0.0f;
#pragma unroll
        for (int f = 0; f < E; f++) te += M[e][E + f] * x[f];
        quad += x[e] * te;
      }
      float qval = a2 * __expf(c0 - 0.5f * quad);
      float bq = beta[d * N + n] * qval;
      acc_mu += bq;
#pragma unroll
      for (int e = 0; e < E; e++) acc_w[e] += bq * x[e];
    }
    int wid = tid >> 6, lane = tid & 63;
    float r = wave_reduce(acc_mu);
    if (lane == 0) wred[wid][0] = r;
#pragma unroll
    for (int e = 0; e < E; e++) {
      r = wave_reduce(acc_w[e]);
      if (lane == 0) wred[wid][e + 1] = r;
    }
    __syncthreads();
    if (tid < 11) {
      float s = wred[0][tid] + wred[1][tid] + wred[2][tid] + wred[3][tid];
      if (tid == 0) ws[OFF_MUD + b * D + d] = s;
      else wsh[tid - 1] = s;
    }
    __syncthreads();
    if (tid == 0) {
      float u[E];
#pragma unroll
      for (int f = 0; f < E; f++) {
        float s = 0.0f;
#pragma unroll
        for (int g = 0; g < E; g++) s += M[f][E + g] * wsh[g];
        u[f] = s;
      }
#pragma unroll
      for (int e = 0; e < E; e++) {
        float s = 0.0f;
#pragma unroll
        for (int f = 0; f < E; f++) s += sSig[e * E + f] * u[f];
        ws[OFF_V + (b * D + d) * E + e] = s;
      }
    }
    return;
  }

  // ===== pair path: W + PA + PB for (p36, b) =====
  if (bx == 0) {   // zero EDD(1024)+TR(128)+ticket before k_q
    for (int idx = tid; idx < 1156; idx += 256) ws[OFF_EDD + idx] = 0.0f;
  }
  int p36 = bx / B, b = bx % B;
  int a, d;
  decode_pair(p36, &a, &d);
  int pb = p36 * B + b;
  if (tid < E) {
    sMu[tid] = (tid < D) ? obs_mean[b * D + tid] : action_mean[b * FDIM + tid - D];
    float la = ell[a * E + tid]; siLa[tid] = 1.0f / (la * la);
    float ldv = ell[d * E + tid]; siLd[tid] = 1.0f / (ldv * ldv);
  }
  for (int idx = tid; idx < E * E; idx += 256) {
    int e = idx / E, f = idx % E;
    float v;
    if (e < D && f < D)      v = obs_var[(b * D + e) * D + f];
    else if (e < D)          v = cross_cov[(b * D + e) * FDIM + (f - D)];
    else if (f < D)          v = cross_cov[(b * D + f) * FDIM + (e - D)];
    else                     v = action_var[(b * FDIM + (e - D)) * FDIM + (f - D)];
    sSig[idx] = v;
  }
  __syncthreads();
  for (int idx = tid; idx < E * GJW; idx += 256) {
    int r = idx / GJW, c = idx % GJW;
    float v;
    if (c < E) v = sSig[r * E + c] * (siLa[c] + siLd[c]) + ((r == c) ? 1.0f : 0.0f);
    else       v = sSig[r * E + (c - E)];
    M[r][c] = v;
  }
  __syncthreads();
  gj_block(M, pivrow, colfac, &s_piv, &s_det, tid);   // M[r][E+c] = S
  float ldr = logf(s_det);
  float lga = logf(alpha_sq[a]);
  float lgd = logf(alpha_sq[d]);
  // W (log2e-folded)
  for (int idx = tid; idx < E * E; idx += 256) {
    int e = idx / E, f = idx % E;
    ws[OFF_W + (size_t)pb * 100 + idx] = LOG2E * siLa[e] * M[e][E + f] * siLd[f];
  }
  // PA/PB per n
  for (int n = tid; n < N; n += 256) {
    float pa[E], pd[E];
    float s2a = 0.0f, s2b = 0.0f;
#pragma unroll
    for (int e = 0; e < E; e++) {
      float xe = X[n * E + e] - sMu[e];
      pa[e] = xe * siLa[e];
      pd[e] = xe * siLd[e];
      s2a += xe * pa[e];
      s2b += xe * pd[e];
    }
    float da = 0.0f, db = 0.0f;
#pragma unroll
    for (int e = 0; e < E; e++) {
      float ta = 0.0f, td = 0.0f;
#pragma unroll
      for (int f = 0; f < E; f++) {
        float s = M[e][E + f];
        ta += s * pa[f];
        td += s * pd[f];
      }
      da += pa[e] * ta;
      db += pd[e] * td;
    }
    float ca = LOG2E * (lga - 0.5f * s2a + 0.5f * da - 0.5f * ldr);
    float cb = LOG2E * (lgd - 0.5f * s2b + 0.5f * db);
    float Ei = fast_exp2(ca);
    float cbE = fast_exp2(cb);
    ((float2*)(ws + OFF_PA))[(size_t)pb * N + n] =
        make_float2(beta[(size_t)a * N + n] * Ei, Ei);
    ((float2*)(ws + OFF_PB))[(size_t)pb * N + n] =
        make_float2(beta[(size_t)d * N + n] * cbE, cbE);
  }
}

// 10-term dot of a T-row (t0,t1,t2) against a j-fragment (xa,xb,xc)
#define DOT10(t0, t1, t2, xa, xb, xc)                                          \
  fmaf(t2.y, xc.y,                                                             \
  fmaf(t2.x, xc.x,                                                             \
  fmaf(t1.w, xb.w,                                                             \
  fmaf(t1.z, xb.z,                                                             \
  fmaf(t1.y, xb.y,                                                             \
  fmaf(t1.x, xb.x,                                                             \
  fmaf(t0.w, xa.w,                                                             \
  fmaf(t0.z, xa.z,                                                             \
  fmaf(t0.y, xa.y, t0.x * xa.x)))))))))

// ---------------------------------------------------------------------------
// k_q: per (pair, b, i-tile). Lane holds 4 j-fragments as NAMED float4s;
// main loop processes TWO T-rows per iteration (6 b128 loads up front, then
// 8 independent DOT10 chains + 8 back-to-back exp2) so LDS latency is
// amortized and the VALU stays packed (round-5 structure, round-9 lean body).
// Last block (ticket) assembles the final output.
__global__ __launch_bounds__(256, 2) void k_q(
    const float* __restrict__ obs_mean, const float* __restrict__ obs_var,
    const float* __restrict__ alpha_sq, const float* __restrict__ sigma_sq_eps,
    const float* __restrict__ invK, float* __restrict__ ws,
    float* __restrict__ out) {
  __shared__ float sT[TIL * 12];     // 6144 B: [t0..t9, baE, Ei] per i-row
  __shared__ float sW[100];
  __shared__ float redw[8];
  __shared__ int s_last;

  int tid = threadIdx.x;
  int bx = blockIdx.x;
  int tile = bx & (NT - 1);
  int rest = bx >> 2;
  int b = rest & (B - 1);
  int p36 = rest >> 4;
  int a, d;
  decode_pair(p36, &a, &d);
  int pb = p36 * B + b;
  bool diag = (a == d);
  int i0 = tile * TIL;

  // ---- load W into LDS ----
  if (tid < 100) sW[tid] = ws[OFF_W + (size_t)pb * 100 + tid];

  // ---- per-lane j fragments: 4 consecutive j from global XNU (named) ----
  int lane = tid & 63;
  int w = tid >> 6;
  int ihalf = w >> 1;
  int jhalf = w & 1;
  int j0 = jhalf * 256 + lane * 4;
  const float4* xp = (const float4*)(ws + OFF_XNU + ((size_t)b * N + j0) * 12);
  float4 xA0 = xp[0], xA1 = xp[1], xA2 = xp[2];
  float4 xB0 = xp[3], xB1 = xp[4], xB2 = xp[5];
  float4 xC0 = xp[6], xC1 = xp[7], xC2 = xp[8];
  float4 xD0 = xp[9], xD1 = xp[10], xD2 = xp[11];
  const float2* pbp = ((const float2*)(ws + OFF_PB)) + (size_t)pb * N + j0;
  float2 pb0 = pbp[0], pb1 = pbp[1], pb2 = pbp[2], pb3 = pbp[3];
  __syncthreads();

  // ---- build sT rows [t, baE, Ei] for own 128 i (threads 0..127) ----
  if (tid < TIL) {
    const float4* xip = (const float4*)(ws + OFF_XNU + ((size_t)b * N + i0 + tid) * 12);
    float4 a0 = xip[0], a1 = xip[1], a2 = xip[2];
    float x[10] = {a0.x, a0.y, a0.z, a0.w, a1.x, a1.y, a1.z, a1.w, a2.x, a2.y};
#pragma unroll
    for (int f = 0; f < E; f++) {
      float acc = 0.0f;
#pragma unroll
      for (int e = 0; e < E; e++) acc += x[e] * sW[e * 10 + f];
      sT[tid * 12 + f] = acc;
    }
    float2 pav = ((const float2*)(ws + OFF_PA))[(size_t)pb * N + i0 + tid];
    sT[tid * 12 + 10] = pav.x;    // baE
    sT[tid * 12 + 11] = pav.y;    // Ei
  }
  __syncthreads();

  // ---- main loop: 2 rows per iteration, 8-way ILP ----
  float accA = 0.0f, accB = 0.0f, accC = 0.0f, accD = 0.0f;
  float trA = 0.0f, trB = 0.0f, trC = 0.0f, trD = 0.0f;
  const float* invKa = invK + (size_t)a * N * N;
  int rbase = ihalf * 64;
#pragma unroll 2
  for (int it = 0; it < 32; it++) {
    int row = rbase + it * 2;
    const float4* tp = (const float4*)&sT[row * 12];
    float4 t0 = tp[0], t1 = tp[1], t2 = tp[2];   // row
    float4 u0 = tp[3], u1 = tp[4], u2 = tp[5];   // row+1
    float4 kv0, kv1;
    if (diag) {
      kv0 = *(const float4*)(invKa + (size_t)(i0 + row) * N + j0);
      kv1 = *(const float4*)(invKa + (size_t)(i0 + row + 1) * N + j0);
    }
    float mA0 = DOT10(t0, t1, t2, xA0, xA1, xA2);
    float mB0 = DOT10(t0, t1, t2, xB0, xB1, xB2);
    float mC0 = DOT10(t0, t1, t2, xC0, xC1, xC2);
    float mD0 = DOT10(t0, t1, t2, xD0, xD1, xD2);
    float mA1 = DOT10(u0, u1, u2, xA0, xA1, xA2);
    float mB1 = DOT10(u0, u1, u2, xB0, xB1, xB2);
    float mC1 = DOT10(u0, u1, u2, xC0, xC1, xC2);
    float mD1 = DOT10(u0, u1, u2, xD0, xD1, xD2);
    float qA0 = fast_exp2(mA0);
    float qB0 = fast_exp2(mB0);
    float qC0 = fast_exp2(mC0);
    float qD0 = fast_exp2(mD0);
    float qA1 = fast_exp2(mA1);
    float qB1 = fast_exp2(mB1);
    float qC1 = fast_exp2(mC1);
    float qD1 = fast_exp2(mD1);
    float baE0 = t2.z, Ei0 = t2.w;
    float baE1 = u2.z, Ei1 = u2.w;
    accA = fmaf(baE0, qA0, accA); accA = fmaf(baE1, qA1, accA);
    accB = fmaf(baE0, qB0, accB); accB = fmaf(baE1, qB1, accB);
    accC = fmaf(baE0, qC0, accC); accC = fmaf(baE1, qC1, accC);
    accD = fmaf(baE0, qD0, accD); accD = fmaf(baE1, qD1, accD);
    if (diag) {
      trA = fmaf(kv0.x, Ei0 * qA0, trA); trA = fmaf(kv1.x, Ei1 * qA1, trA);
      trB = fmaf(kv0.y, Ei0 * qB0, trB); trB = fmaf(kv1.y, Ei1 * qB1, trB);
      trC = fmaf(kv0.z, Ei0 * qC0, trC); trC = fmaf(kv1.z, Ei1 * qC1, trC);
      trD = fmaf(kv0.w, Ei0 * qD0, trD); trD = fmaf(kv1.w, Ei1 * qD1, trD);
    }
  }

  // ---- fold per-j factors, reduce, atomic accumulate, ticket ----
  float local = pb0.x * accA + pb1.x * accB + pb2.x * accC + pb3.x * accD;
  float local_tr = diag ? (pb0.y * trA + pb1.y * trB + pb2.y * trC + pb3.y * trD)
                        : 0.0f;
  {
    float rr = wave_reduce(local);
    if (lane == 0) redw[w] = rr;
    if (diag) {
      float rt = wave_reduce(local_tr);
      if (lane == 0) redw[4 + w] = rt;
    }
    __syncthreads();
    if (tid == 0) {
      float v = redw[0] + redw[1] + redw[2] + redw[3];
      atomicAdd(&ws[OFF_EDD + b * (D * D) + a * D + d], v);
      if (!diag) {
        atomicAdd(&ws[OFF_EDD + b * (D * D) + d * D + a], v);
      } else {
        atomicAdd(&ws[OFF_TR + b * D + a], redw[4] + redw[5] + redw[6] + redw[7]);
      }
      __threadfence();
      int old = atomicAdd((int*)(ws + OFF_TICKET), 1);
      s_last = (old == NQ - 1);
    }
    __syncthreads();
  }

  // ---- last block assembles the output ----
  if (s_last) {
    __threadfence();
    for (int m = tid; m < B * D; m += 256) {
      out[m] = obs_mean[m] + ws[OFF_MUD + m];
    }
    for (int cell = tid; cell < B * D * D; cell += 256) {
      int b2 = cell >> 6, ij = cell & 63;
      int i = ij >> 3, j = ij & 7;
      float edd = atomicAdd(&ws[OFF_EDD + cell], 0.0f);   // coherent read
      float mi = ws[OFF_MUD + b2 * D + i];
      float mj = ws[OFF_MUD + b2 * D + j];
      float sd = edd - mi * mj;
      if (i == j) {
        float tr = atomicAdd(&ws[OFF_TR + b2 * D + i], 0.0f);
        sd += alpha_sq[i] - tr + sigma_sq_eps[i];
      }
      float cxd = ws[OFF_V + (b2 * D + j) * E + i];   // C_xd[b,i,j] = V[b,j,i]
      float cdx = ws[OFF_V + (b2 * D + i) * E + j];
      out[B * D + cell] = obs_var[cell] + sd + cxd + cdx;
    }
  }
}

// ---------------------------------------------------------------------------
extern "C" void kernel_launch(void* const* d_in, const int* in_sizes, int n_in,
                              void* d_out, int out_size, void* d_ws, size_t ws_size,
                              hipStream_t stream) {
  const float* obs_mean     = (const float*)d_in[0];
  const float* obs_var      = (const float*)d_in[1];
  const float* action_mean  = (const float*)d_in[2];
  const float* action_var   = (const float*)d_in[3];
  const float* cross_cov    = (const float*)d_in[4];
  const float* X_train      = (const float*)d_in[5];
  const float* ell          = (const float*)d_in[6];
  const float* alpha_sq     = (const float*)d_in[7];
  const float* sigma_sq_eps = (const float*)d_in[8];
  const float* beta         = (const float*)d_in[9];
  const float* inv_K        = (const float*)d_in[10];
  float* out = (float*)d_out;
  float* ws = (float*)d_ws;

  k_prep<<<NPREP, 256, 0, stream>>>(obs_mean, obs_var, action_mean, action_var,
                                    cross_cov, X_train, ell, alpha_sq, beta, ws);
  k_q<<<NQ, 256, 0, stream>>>(obs_mean, obs_var, alpha_sq, sigma_sq_eps,
                              inv_K, ws, out);
}